// Round 1
// baseline (164.441 us; speedup 1.0000x reference)
//
#include <hip/hip_runtime.h>

// DepthwiseConv3D: x(8,64,64,32,64) fp32, w(32,3,3,64), b(32,64)
// y[b,h,w,d,c] = sum_{kh,kw} x[b,h+kh-1,w+kw-1,d,c]*w[d,kh,kw,c] + b[d,c]
// Layout (floats): x stride: c=1, d=64, w=2048, h=131072, b=8388608
// float4 units:          c4=1, d=16, w=512,  h=32768,  b=2097152

#define WS 4  // w-outputs per thread (sliding window)

__device__ __forceinline__ float4 f4zero() { return make_float4(0.f, 0.f, 0.f, 0.f); }

__device__ __forceinline__ void fma4(float4& acc, const float4 a, const float4 w) {
  acc.x = fmaf(a.x, w.x, acc.x);
  acc.y = fmaf(a.y, w.y, acc.y);
  acc.z = fmaf(a.z, w.z, acc.z);
  acc.w = fmaf(a.w, w.w, acc.w);
}

__global__ __launch_bounds__(256) void DepthwiseConv3D_kernel(
    const float4* __restrict__ x, const float4* __restrict__ wgt,
    const float4* __restrict__ bias, float4* __restrict__ y) {
  const int tid = blockIdx.x * 256 + threadIdx.x;
  // bit decomposition: c4[0:3] d[4:8] ws[9:12] h[13:18] b[19:21]
  const int c4 = tid & 15;         // C/4 = 16
  const int d  = (tid >> 4) & 31;  // D = 32
  const int ws = (tid >> 9) & 15;  // W/WS = 16 strips
  const int h  = (tid >> 13) & 63; // H = 64
  const int b  = tid >> 19;        // B = 8
  const int w0 = ws * WS;

  // weights: w[d,kh,kw,c] float4 index = d*144 + kh*48 + kw*16 + c4
  float4 wt[3][3];
#pragma unroll
  for (int kh = 0; kh < 3; ++kh)
#pragma unroll
    for (int kw = 0; kw < 3; ++kw)
      wt[kh][kw] = wgt[d * 144 + kh * 48 + kw * 16 + c4];
  const float4 bv = bias[d * 16 + c4];

  // base float4 index of (b, h, w=0, d, c4)
  const int base = ((b * 64 + h) * 64) * 512 + d * 16 + c4;
  const bool hm = (h > 0), hp = (h < 63);

  float4 cm[3], cc[3], cp[3];

  auto loadcol = [&](int wc, float4* col) {
    if (wc < 0 || wc > 63) {
      col[0] = f4zero(); col[1] = f4zero(); col[2] = f4zero();
      return;
    }
    const int p = base + wc * 512;
    col[0] = hm ? x[p - 32768] : f4zero();
    col[1] = x[p];
    col[2] = hp ? x[p + 32768] : f4zero();
  };

  loadcol(w0 - 1, cm);
  loadcol(w0,     cc);
#pragma unroll
  for (int i = 0; i < WS; ++i) {
    loadcol(w0 + i + 1, cp);
    float4 acc = bv;
#pragma unroll
    for (int r = 0; r < 3; ++r) {
      fma4(acc, cm[r], wt[r][0]);
      fma4(acc, cc[r], wt[r][1]);
      fma4(acc, cp[r], wt[r][2]);
    }
    y[base + (w0 + i) * 512] = acc;
#pragma unroll
    for (int r = 0; r < 3; ++r) { cm[r] = cc[r]; cc[r] = cp[r]; }
  }
}

extern "C" void kernel_launch(void* const* d_in, const int* in_sizes, int n_in,
                              void* d_out, int out_size, void* d_ws, size_t ws_size,
                              hipStream_t stream) {
  const float4* x    = (const float4*)d_in[0];
  const float4* wgt  = (const float4*)d_in[1];
  const float4* bias = (const float4*)d_in[2];
  float4* y          = (float4*)d_out;
  // total threads = 8*64*16*32*16 = 4,194,304 -> 16384 blocks of 256
  DepthwiseConv3D_kernel<<<16384, 256, 0, stream>>>(x, wgt, bias, y);
}

// Round 2
// 98.520 us; speedup vs baseline: 1.6691x; 1.6691x over previous
//
#include <hip/hip_runtime.h>

// DepthwiseConv3D: x(8,64,64,32,64) fp32, w(32,3,3,64), b(32,64)
// y[b,h,w,d,c] = sum_{kh,kw} x[b,h+kh-1,w+kw-1,d,c]*w[d,kh,kw,c] + b[d,c]
// float4 strides: c4=1, d=16, w=512, h=32768, b=2097152

typedef float v4 __attribute__((ext_vector_type(4)));

__global__ __launch_bounds__(256) void DepthwiseConv3D_kernel(
    const v4* __restrict__ x, const v4* __restrict__ wgt,
    const v4* __restrict__ bias, v4* __restrict__ y) {
  const int tid = blockIdx.x * 256 + threadIdx.x;
  // c4[0:3] d[4:8] ws[9:12] h[13:18] b[19:21]
  const int c4 = tid & 15;         // C/4 = 16
  const int d  = (tid >> 4) & 31;  // D = 32
  const int ws = (tid >> 9) & 15;  // 16 strips of WS=4
  const int h  = (tid >> 13) & 63; // H = 64
  const int b  = tid >> 19;        // B = 8
  const int w0 = ws * 4;

  const int base = ((b * 64 + h) * 64) * 512 + d * 16 + c4;
  const bool hm = (h > 0), hp = (h < 63);
  const v4 z = (v4)(0.f);

  // Hoist ALL x loads (6 cols x 3 rows) before any compute: max MLP.
  // Issue order = consumption order so waitcnts are incremental.
  v4 col[6][3];
#pragma unroll
  for (int j = 0; j < 6; ++j) {
    const int wc = w0 - 1 + j;
    const bool wok = ((unsigned)wc) < 64u;
    const int p = base + wc * 512;
    col[j][0] = (wok && hm) ? x[p - 32768] : z;
    col[j][1] = (wok)       ? x[p]         : z;
    col[j][2] = (wok && hp) ? x[p + 32768] : z;
  }

  // Weights/bias after x (these are L2-resident after the first blocks).
  v4 wt[3][3];
#pragma unroll
  for (int kh = 0; kh < 3; ++kh)
#pragma unroll
    for (int kw = 0; kw < 3; ++kw)
      wt[kh][kw] = wgt[d * 144 + kh * 48 + kw * 16 + c4];
  const v4 bv = bias[d * 16 + c4];

  v4 acc[4];
#pragma unroll
  for (int i = 0; i < 4; ++i) acc[i] = bv;
#pragma unroll
  for (int i = 0; i < 4; ++i) {
#pragma unroll
    for (int r = 0; r < 3; ++r) {
      acc[i] += col[i][r]     * wt[r][0];
      acc[i] += col[i + 1][r] * wt[r][1];
      acc[i] += col[i + 2][r] * wt[r][2];
    }
  }

  // Nontemporal: y is never re-read; keep L3 for x's 3-row reuse.
#pragma unroll
  for (int i = 0; i < 4; ++i)
    __builtin_nontemporal_store(acc[i], &y[base + (w0 + i) * 512]);
}

extern "C" void kernel_launch(void* const* d_in, const int* in_sizes, int n_in,
                              void* d_out, int out_size, void* d_ws, size_t ws_size,
                              hipStream_t stream) {
  const v4* x    = (const v4*)d_in[0];
  const v4* wgt  = (const v4*)d_in[1];
  const v4* bias = (const v4*)d_in[2];
  v4* y          = (v4*)d_out;
  // 8*64*16*32*16 = 4,194,304 threads -> 16384 blocks of 256
  DepthwiseConv3D_kernel<<<16384, 256, 0, stream>>>(x, wgt, bias, y);
}

// Round 3
// 95.529 us; speedup vs baseline: 1.7214x; 1.0313x over previous
//
#include <hip/hip_runtime.h>

// DepthwiseConv3D: x(8,64,64,32,64) fp32, w(32,3,3,64), b(32,64)
// y[b,h,w,d,c] = sum_{kh,kw} x[b,h+kh-1,w+kw-1,d,c]*w[d,kh,kw,c] + b[d,c]
// float4 strides: c4=1, d=16, w=512, h=32768, b=2097152
// Per-thread tile: 4 w-outputs x 2 h-outputs (8 outputs), 24 x-loads fully
// hoisted (MLP=24). launch_bounds(256,3) caps VGPR at ~170 so the 24-col
// window (96 VGPR) + weights (36) + acc (32) stays in registers.

typedef float v4 __attribute__((ext_vector_type(4)));

__global__ __launch_bounds__(256, 3) void DepthwiseConv3D_kernel(
    const v4* __restrict__ x, const v4* __restrict__ wgt,
    const v4* __restrict__ bias, v4* __restrict__ y) {
  const int tid = blockIdx.x * 256 + threadIdx.x;
  // c4[0:3] d[4:8] ws[9:12] h2[13:17] b[18:20]
  const int c4 = tid & 15;         // C/4 = 16
  const int d  = (tid >> 4) & 31;  // D = 32
  const int ws = (tid >> 9) & 15;  // 16 strips of 4
  const int h2 = (tid >> 13) & 31; // 32 pairs of h-rows
  const int b  = tid >> 18;        // B = 8
  const int h  = h2 * 2;
  const int w0 = ws * 4;

  const int base = ((b * 64 + h) * 64) * 512 + d * 16 + c4;  // (b,h,0,d,c4)
  const bool r0ok = (h2 > 0);   // row h-1 exists
  const bool r3ok = (h2 < 31);  // row h+2 exists
  const v4 z = (v4)(0.f);

  // Hoist ALL 24 x-loads (6 w-cols x 4 h-rows) before any compute.
  v4 col[6][4];
#pragma unroll
  for (int j = 0; j < 6; ++j) {
    const int wc = w0 - 1 + j;
    const bool wok = ((unsigned)wc) < 64u;
    const int p = base + wc * 512;
    col[j][0] = (wok && r0ok) ? x[p - 32768] : z;
    col[j][1] = wok           ? x[p]         : z;
    col[j][2] = wok           ? x[p + 32768] : z;
    col[j][3] = (wok && r3ok) ? x[p + 65536] : z;
  }

  // Weights/bias after x-loads (L2-resident, cheap).
  v4 wt[3][3];
#pragma unroll
  for (int kh = 0; kh < 3; ++kh)
#pragma unroll
    for (int kw = 0; kw < 3; ++kw)
      wt[kh][kw] = wgt[d * 144 + kh * 48 + kw * 16 + c4];
  const v4 bv = bias[d * 16 + c4];

  v4 acc[2][4];
#pragma unroll
  for (int hh = 0; hh < 2; ++hh)
#pragma unroll
    for (int i = 0; i < 4; ++i) acc[hh][i] = bv;

#pragma unroll
  for (int i = 0; i < 4; ++i)
#pragma unroll
    for (int kh = 0; kh < 3; ++kh)
#pragma unroll
      for (int kw = 0; kw < 3; ++kw) {
        acc[0][i] += col[i + kw][kh]     * wt[kh][kw];  // output row h
        acc[1][i] += col[i + kw][kh + 1] * wt[kh][kw];  // output row h+1
      }

  // Nontemporal: y never re-read; keep L2/L3 for x's halo reuse.
#pragma unroll
  for (int hh = 0; hh < 2; ++hh)
#pragma unroll
    for (int i = 0; i < 4; ++i)
      __builtin_nontemporal_store(acc[hh][i],
                                  &y[base + hh * 32768 + (w0 + i) * 512]);
}

extern "C" void kernel_launch(void* const* d_in, const int* in_sizes, int n_in,
                              void* d_out, int out_size, void* d_ws, size_t ws_size,
                              hipStream_t stream) {
  const v4* x    = (const v4*)d_in[0];
  const v4* wgt  = (const v4*)d_in[1];
  const v4* bias = (const v4*)d_in[2];
  v4* y          = (v4*)d_out;
  // 8*32*16*32*16 = 2,097,152 threads -> 8192 blocks of 256
  DepthwiseConv3D_kernel<<<8192, 256, 0, stream>>>(x, wgt, bias, y);
}

// Round 4
// 85.531 us; speedup vs baseline: 1.9226x; 1.1169x over previous
//
#include <hip/hip_runtime.h>

// DepthwiseConv3D: x(8,64,64,32,64) fp32, w(32,3,3,64), b(32,64)
// y[b,h,w,d,c] = sum_{kh,kw} x[b,h+kh-1,w+kw-1,d,c]*w[d,kh,kw,c] + b[d,c]
// float4 strides: c4=1, d=16, w=512, h=32768, b=2097152
//
// R4 change: XCD-chunked block swizzle. 8192 blocks round-robin across 8
// XCDs (blockIdx%8 = XCD, m09), so we put b = blockIdx&7: batch b lives
// entirely on XCD b. Within the chunk, h2-major ordering keeps the 4-row
// halo window (~3 MB of full-W rows) inside the 4 MiB per-XCD L2, turning
// the 3x row reuse into L2 hits instead of Infinity-Fabric/L3 traffic.

typedef float v4 __attribute__((ext_vector_type(4)));

__global__ __launch_bounds__(256, 3) void DepthwiseConv3D_kernel(
    const v4* __restrict__ x, const v4* __restrict__ wgt,
    const v4* __restrict__ bias, v4* __restrict__ y) {
  // Block decomposition: b = blk&7 (XCD id); local = blk>>3:
  //   dhi = local&1, ws = (local>>1)&15, h2 = (local>>5)&31  (h2-major)
  const int blk = blockIdx.x;
  const int b   = blk & 7;
  const int loc = blk >> 3;
  const int dhi = loc & 1;
  const int ws  = (loc >> 1) & 15;
  const int h2  = (loc >> 5) & 31;
  // Thread decomposition: c4 = t&15, dlo = t>>4
  const int c4  = threadIdx.x & 15;
  const int dlo = threadIdx.x >> 4;
  const int d   = (dhi << 4) | dlo;
  const int h   = h2 * 2;
  const int w0  = ws * 4;

  const int base = ((b * 64 + h) * 64) * 512 + d * 16 + c4;  // (b,h,0,d,c4)
  const bool r0ok = (h2 > 0);   // row h-1 exists
  const bool r3ok = (h2 < 31);  // row h+2 exists
  const v4 z = (v4)(0.f);

  // Hoist ALL 24 x-loads (6 w-cols x 4 h-rows) before any compute.
  v4 col[6][4];
#pragma unroll
  for (int j = 0; j < 6; ++j) {
    const int wc = w0 - 1 + j;
    const bool wok = ((unsigned)wc) < 64u;
    const int p = base + wc * 512;
    col[j][0] = (wok && r0ok) ? x[p - 32768] : z;
    col[j][1] = wok           ? x[p]         : z;
    col[j][2] = wok           ? x[p + 32768] : z;
    col[j][3] = (wok && r3ok) ? x[p + 65536] : z;
  }

  // Weights/bias after x-loads (L2-resident, cheap).
  v4 wt[3][3];
#pragma unroll
  for (int kh = 0; kh < 3; ++kh)
#pragma unroll
    for (int kw = 0; kw < 3; ++kw)
      wt[kh][kw] = wgt[d * 144 + kh * 48 + kw * 16 + c4];
  const v4 bv = bias[d * 16 + c4];

  v4 acc[2][4];
#pragma unroll
  for (int hh = 0; hh < 2; ++hh)
#pragma unroll
    for (int i = 0; i < 4; ++i) acc[hh][i] = bv;

#pragma unroll
  for (int i = 0; i < 4; ++i)
#pragma unroll
    for (int kh = 0; kh < 3; ++kh)
#pragma unroll
      for (int kw = 0; kw < 3; ++kw) {
        acc[0][i] += col[i + kw][kh]     * wt[kh][kw];  // output row h
        acc[1][i] += col[i + kw][kh + 1] * wt[kh][kw];  // output row h+1
      }

  // Nontemporal: y never re-read; keep L2 for x's halo reuse.
#pragma unroll
  for (int hh = 0; hh < 2; ++hh)
#pragma unroll
    for (int i = 0; i < 4; ++i)
      __builtin_nontemporal_store(acc[hh][i],
                                  &y[base + hh * 32768 + (w0 + i) * 512]);
}

extern "C" void kernel_launch(void* const* d_in, const int* in_sizes, int n_in,
                              void* d_out, int out_size, void* d_ws, size_t ws_size,
                              hipStream_t stream) {
  const v4* x    = (const v4*)d_in[0];
  const v4* wgt  = (const v4*)d_in[1];
  const v4* bias = (const v4*)d_in[2];
  v4* y          = (v4*)d_out;
  // 8 XCDs x 1024 blocks (1 batch per XCD), 256 threads each
  DepthwiseConv3D_kernel<<<8192, 256, 0, stream>>>(x, wgt, bias, y);
}

// Round 5
// 84.521 us; speedup vs baseline: 1.9456x; 1.0120x over previous
//
#include <hip/hip_runtime.h>

// DepthwiseConv3D: x(8,64,64,32,64) fp32, w(32,3,3,64), b(32,64)
// y[b,h,w,d,c] = sum_{kh,kw} x[b,h+kh-1,w+kw-1,d,c]*w[d,kh,kw,c] + b[d,c]
// float4 strides: c4=1, d=16, w=512, h=32768, b=2097152
//
// R5: 4h x 4w per-thread tile (16 outputs, 36 loads = 2.25 taps/output,
// down from 3.0). Halves wave count, cuts logical read traffic 25% to
// relieve the L2/L3/fabric path. XCD-chunked swizzle kept: b = blk&7
// (one batch per XCD), h4-major in-chunk so the 6-row halo window
// (6 x 512 KB = 3 MB) stays inside the 4 MiB per-XCD L2.

typedef float v4 __attribute__((ext_vector_type(4)));

__global__ __launch_bounds__(256, 2) void DepthwiseConv3D_kernel(
    const v4* __restrict__ x, const v4* __restrict__ wgt,
    const v4* __restrict__ bias, v4* __restrict__ y) {
  // Block: b = blk&7 (XCD id); loc = blk>>3: dhi[0] ws[1:4] h4[5:8]
  const int blk = blockIdx.x;
  const int b   = blk & 7;
  const int loc = blk >> 3;
  const int dhi = loc & 1;
  const int ws  = (loc >> 1) & 15;
  const int h4  = loc >> 5;          // 0..15
  // Thread: c4 = t&15, dlo = t>>4
  const int c4  = threadIdx.x & 15;
  const int dlo = threadIdx.x >> 4;
  const int d   = (dhi << 4) | dlo;
  const int h   = h4 * 4;
  const int w0  = ws * 4;

  const int base = ((b * 64 + h) * 64) * 512 + d * 16 + c4;  // (b,h,0,d,c4)
  const bool rtop = (h4 > 0);   // row h-1 exists
  const bool rbot = (h4 < 15);  // row h+4 exists
  const v4 z = (v4)(0.f);

  // Hoist all 36 x-loads (6 w-cols x 6 h-rows: h-1 .. h+4).
  v4 col[6][6];
#pragma unroll
  for (int j = 0; j < 6; ++j) {
    const int wc = w0 - 1 + j;
    const bool wok = ((unsigned)wc) < 64u;
    const int p = base + wc * 512;
    col[j][0] = (wok && rtop) ? x[p - 32768] : z;
#pragma unroll
    for (int r = 1; r < 5; ++r)
      col[j][r] = wok ? x[p + (r - 1) * 32768] : z;
    col[j][5] = (wok && rbot) ? x[p + 131072] : z;
  }

  // Weights/bias after x-loads (L2-resident, cheap).
  v4 wt[3][3];
#pragma unroll
  for (int kh = 0; kh < 3; ++kh)
#pragma unroll
    for (int kw = 0; kw < 3; ++kw)
      wt[kh][kw] = wgt[d * 144 + kh * 48 + kw * 16 + c4];
  const v4 bv = bias[d * 16 + c4];

  v4 acc[4][4];
#pragma unroll
  for (int hh = 0; hh < 4; ++hh)
#pragma unroll
    for (int i = 0; i < 4; ++i) acc[hh][i] = bv;

#pragma unroll
  for (int kh = 0; kh < 3; ++kh)
#pragma unroll
    for (int kw = 0; kw < 3; ++kw)
#pragma unroll
      for (int hh = 0; hh < 4; ++hh)
#pragma unroll
        for (int i = 0; i < 4; ++i)
          acc[hh][i] += col[i + kw][hh + kh] * wt[kh][kw];

  // Nontemporal: y never re-read; keep L2 for x's halo reuse.
#pragma unroll
  for (int hh = 0; hh < 4; ++hh)
#pragma unroll
    for (int i = 0; i < 4; ++i)
      __builtin_nontemporal_store(acc[hh][i],
                                  &y[base + hh * 32768 + (w0 + i) * 512]);
}

extern "C" void kernel_launch(void* const* d_in, const int* in_sizes, int n_in,
                              void* d_out, int out_size, void* d_ws, size_t ws_size,
                              hipStream_t stream) {
  const v4* x    = (const v4*)d_in[0];
  const v4* wgt  = (const v4*)d_in[1];
  const v4* bias = (const v4*)d_in[2];
  v4* y          = (v4*)d_out;
  // 8 XCDs x 512 blocks (1 batch per XCD): 16 h4 x 16 ws x 2 dhi
  DepthwiseConv3D_kernel<<<4096, 256, 0, stream>>>(x, wgt, bias, y);
}